// Round 2
// baseline (9025.330 us; speedup 1.0000x reference)
//
#include <hip/hip_runtime.h>
#include <cmath>

// B=32, S=512, T=64, IN=512, H=512, L=2, HC=4, OUT=512

__device__ __forceinline__ float sigmoidf_(float x) { return 1.f / (1.f + __expf(-x)); }

__device__ __forceinline__ float wave_sum(float v) {
#pragma unroll
  for (int m = 1; m < 64; m <<= 1) v += __shfl_xor(v, m, 64);
  return v;
}
__device__ __forceinline__ float wave_max(float v) {
#pragma unroll
  for (int m = 1; m < 64; m <<= 1) v = fmaxf(v, __shfl_xor(v, m, 64));
  return v;
}
__device__ __forceinline__ void ld8(const float* __restrict__ p, float* d) {
  float4 v0 = *(const float4*)p, v1 = *(const float4*)(p + 4);
  d[0]=v0.x; d[1]=v0.y; d[2]=v0.z; d[3]=v0.w; d[4]=v1.x; d[5]=v1.y; d[6]=v1.z; d[7]=v1.w;
}

// ---- init: h1 <- fh[1]; c0,c1 <- 0; xcat0 h0-slot <- fh[0] ------------------
__global__ void k_init(const float* __restrict__ fh, float* h1, float* c0, float* c1,
                       float* xcat0) {
  int i = blockIdx.x * 256 + threadIdx.x;  // 16384
  int b = i >> 9, hh = i & 511;
  h1[i] = fh[16384 + i]; c0[i] = 0.f; c1[i] = 0.f;
  xcat0[b * 3072 + 2560 + hh] = fh[i];
}

// ---- hid_proj[r][n] = sum_k hiddens[r][k] * Wa1[n][512+k] -------------------
__global__ void k_hidproj(const float* __restrict__ hid, const float* __restrict__ Wa1,
                          float* __restrict__ hp) {
  __shared__ float As[64][33];
  __shared__ float Bs[64][33];
  int tid = threadIdx.x;
  int r0 = blockIdx.x * 64;
  int n0 = blockIdx.y * 64;
  int tm = (tid >> 4) << 2;
  int tn = (tid & 15) << 2;
  int lr = tid >> 2, lk = (tid & 3) << 3;
  float acc[4][4] = {};
  for (int k0 = 0; k0 < 512; k0 += 32) {
    float4 a0 = *(const float4*)&hid[(r0 + lr) * 512 + k0 + lk];
    float4 a1 = *(const float4*)&hid[(r0 + lr) * 512 + k0 + lk + 4];
    float4 b0 = *(const float4*)&Wa1[(n0 + lr) * 1024 + 512 + k0 + lk];
    float4 b1 = *(const float4*)&Wa1[(n0 + lr) * 1024 + 512 + k0 + lk + 4];
    __syncthreads();
    As[lr][lk+0]=a0.x; As[lr][lk+1]=a0.y; As[lr][lk+2]=a0.z; As[lr][lk+3]=a0.w;
    As[lr][lk+4]=a1.x; As[lr][lk+5]=a1.y; As[lr][lk+6]=a1.z; As[lr][lk+7]=a1.w;
    Bs[lr][lk+0]=b0.x; Bs[lr][lk+1]=b0.y; Bs[lr][lk+2]=b0.z; Bs[lr][lk+3]=b0.w;
    Bs[lr][lk+4]=b1.x; Bs[lr][lk+5]=b1.y; Bs[lr][lk+6]=b1.z; Bs[lr][lk+7]=b1.w;
    __syncthreads();
#pragma unroll 8
    for (int kk = 0; kk < 32; kk++) {
      float av[4], bv[4];
#pragma unroll
      for (int i = 0; i < 4; i++) av[i] = As[tm + i][kk];
#pragma unroll
      for (int j = 0; j < 4; j++) bv[j] = Bs[tn + j][kk];
#pragma unroll
      for (int i = 0; i < 4; i++)
#pragma unroll
        for (int j = 0; j < 4; j++) acc[i][j] += av[i] * bv[j];
    }
  }
#pragma unroll
  for (int i = 0; i < 4; i++) {
    float4 v = make_float4(acc[i][0], acc[i][1], acc[i][2], acc[i][3]);
    *(float4*)&hp[(r0 + tm + i) * 512 + n0 + tn] = v;
  }
}

// ---- generic skinny GEMM (M=32) with k-split partials -----------------------
// part[(split*32+b)*J + j] = sum_k x[b][k]*W(j,k), W(j,k)=k<kbound?W1[j][k]:W2[j][k-kbound]
__global__ void k_skinny(const float* __restrict__ x, int K,
                         const float* __restrict__ W1, int ld1,
                         const float* __restrict__ W2, int ld2, int kbound,
                         int chunks_per_split, float* __restrict__ part, int J) {
  __shared__ float xs[32][65];
  __shared__ float ws[64][65];
  int tid = threadIdx.x;
  int j0 = blockIdx.x << 6;
  int jl = (tid & 31) << 1;
  int bl = (tid >> 5) << 2;
  int lb = tid >> 3, lk = (tid & 7) << 3;
  int lj = tid >> 2, lwk = (tid & 3) << 4;
  float acc[4][2] = {};
  for (int c = 0; c < chunks_per_split; c++) {
    int k0 = (blockIdx.y * chunks_per_split + c) << 6;
    float4 xv0 = *(const float4*)&x[lb * K + k0 + lk];
    float4 xv1 = *(const float4*)&x[lb * K + k0 + lk + 4];
    const float* Wp = (k0 < kbound) ? (W1 + (j0 + lj) * ld1 + k0)
                                    : (W2 + (j0 + lj) * ld2 + (k0 - kbound));
    float4 wv0 = *(const float4*)&Wp[lwk];
    float4 wv1 = *(const float4*)&Wp[lwk + 4];
    float4 wv2 = *(const float4*)&Wp[lwk + 8];
    float4 wv3 = *(const float4*)&Wp[lwk + 12];
    __syncthreads();
    xs[lb][lk+0]=xv0.x; xs[lb][lk+1]=xv0.y; xs[lb][lk+2]=xv0.z; xs[lb][lk+3]=xv0.w;
    xs[lb][lk+4]=xv1.x; xs[lb][lk+5]=xv1.y; xs[lb][lk+6]=xv1.z; xs[lb][lk+7]=xv1.w;
    ws[lj][lwk+0]=wv0.x; ws[lj][lwk+1]=wv0.y; ws[lj][lwk+2]=wv0.z; ws[lj][lwk+3]=wv0.w;
    ws[lj][lwk+4]=wv1.x; ws[lj][lwk+5]=wv1.y; ws[lj][lwk+6]=wv1.z; ws[lj][lwk+7]=wv1.w;
    ws[lj][lwk+8]=wv2.x; ws[lj][lwk+9]=wv2.y; ws[lj][lwk+10]=wv2.z; ws[lj][lwk+11]=wv2.w;
    ws[lj][lwk+12]=wv3.x; ws[lj][lwk+13]=wv3.y; ws[lj][lwk+14]=wv3.z; ws[lj][lwk+15]=wv3.w;
    __syncthreads();
#pragma unroll 16
    for (int kk = 0; kk < 64; kk++) {
      float w0 = ws[jl][kk], w1 = ws[jl + 1][kk];
      float x0 = xs[bl][kk], x1 = xs[bl + 1][kk], x2 = xs[bl + 2][kk], x3 = xs[bl + 3][kk];
      acc[0][0] += x0 * w0; acc[0][1] += x0 * w1;
      acc[1][0] += x1 * w0; acc[1][1] += x1 * w1;
      acc[2][0] += x2 * w0; acc[2][1] += x2 * w1;
      acc[3][0] += x3 * w0; acc[3][1] += x3 * w1;
    }
  }
#pragma unroll
  for (int i = 0; i < 4; i++) {
    int r = (blockIdx.y * 32 + bl + i) * J + j0 + jl;
    part[r] = acc[i][0]; part[r + 1] = acc[i][1];
  }
}

// ---- scores[b][k][s] = relu( Wa2 @ relu(mask*q + hp + ba1) + ba2 ) ----------
// q[b][h] = sum of 4 k-split partials in partQ
__global__ void k_scores(const float* __restrict__ hp, const float* __restrict__ partQ,
                         const float* __restrict__ ba1, const float* __restrict__ Wa2,
                         const float* __restrict__ ba2, const int* __restrict__ lengths,
                         float* __restrict__ scores) {
  int w = threadIdx.x >> 6, l = threadIdx.x & 63;
  int row = (blockIdx.x << 2) + w;  // b*512+s
  int b = row >> 9, s = row & 511;
  int kb = l << 3;
  float wv[4][8];
#pragma unroll
  for (int k = 0; k < 4; k++) ld8(&Wa2[k * 512 + kb], wv[k]);
  float bb[8]; ld8(&ba1[kb], bb);
  float qv[8];
  {
    float t0[8], t1[8], t2[8], t3[8];
    ld8(&partQ[(0 * 32 + b) * 512 + kb], t0);
    ld8(&partQ[(1 * 32 + b) * 512 + kb], t1);
    ld8(&partQ[(2 * 32 + b) * 512 + kb], t2);
    ld8(&partQ[(3 * 32 + b) * 512 + kb], t3);
#pragma unroll
    for (int j = 0; j < 8; j++) qv[j] = t0[j] + t1[j] + t2[j] + t3[j];
  }
  float hv[8]; ld8(&hp[row * 512 + kb], hv);
  float m = (s < lengths[b]) ? 1.f : 0.f;
  float sc[4] = {0.f, 0.f, 0.f, 0.f};
#pragma unroll
  for (int j = 0; j < 8; j++) {
    float a = fmaxf(hv[j] + m * qv[j] + bb[j], 0.f);
    sc[0] += wv[0][j] * a; sc[1] += wv[1][j] * a;
    sc[2] += wv[2][j] * a; sc[3] += wv[3][j] * a;
  }
#pragma unroll
  for (int k = 0; k < 4; k++) sc[k] = wave_sum(sc[k]);
  if (l == 0) {
#pragma unroll
    for (int k = 0; k < 4; k++) scores[(b * 4 + k) * 512 + s] = fmaxf(sc[k] + ba2[k], 0.f);
  }
}

// ---- softmax over s + context vectors + build xcat0[0:2560] -----------------
// one block per b; writes xcat0[b][0:512]=inputs_t, [512:2560]=cvec
__global__ void __launch_bounds__(512) k_smcvec(const float* __restrict__ scores,
                                                const float* __restrict__ hiddens,
                                                const float* __restrict__ inputs, int t,
                                                float* __restrict__ xcat0) {
  __shared__ float smx[4 * 512];  // [k][s]
  __shared__ float wred[8], wsum[8];
  int b = blockIdx.x, tid = threadIdx.x;
  int w = tid >> 6, l = tid & 63;
  int k = w >> 1;
  int s4 = ((w & 1) * 64 + l) * 4;
#pragma unroll
  for (int kk = 0; kk < 4; kk++) smx[kk * 512 + tid] = scores[(b * 4 + kk) * 512 + tid];
  __syncthreads();
  float4 v = *(float4*)&smx[k * 512 + s4];
  float mx = fmaxf(fmaxf(v.x, v.y), fmaxf(v.z, v.w));
  mx = wave_max(mx);
  if (l == 0) wred[w] = mx;
  __syncthreads();
  mx = fmaxf(wred[k * 2], wred[k * 2 + 1]);
  float e0 = __expf(v.x - mx), e1 = __expf(v.y - mx);
  float e2 = __expf(v.z - mx), e3 = __expf(v.w - mx);
  float sm = wave_sum(e0 + e1 + e2 + e3);
  if (l == 0) wsum[w] = sm;
  __syncthreads();
  float inv = 1.f / (wsum[k * 2] + wsum[k * 2 + 1]);
  *(float4*)&smx[k * 512 + s4] = make_float4(e0 * inv, e1 * inv, e2 * inv, e3 * inv);
  xcat0[b * 3072 + tid] = inputs[(b * 64 + t) * 512 + tid];
  __syncthreads();
  float a0 = 0.f, a1 = 0.f, a2 = 0.f, a3 = 0.f;
  const float* hb = hiddens + b * 512 * 512 + tid;
  for (int s = 0; s < 512; s += 4) {
    float h0v = hb[(s + 0) * 512];
    float h1v = hb[(s + 1) * 512];
    float h2v = hb[(s + 2) * 512];
    float h3v = hb[(s + 3) * 512];
    a0 += smx[s] * h0v + smx[s + 1] * h1v + smx[s + 2] * h2v + smx[s + 3] * h3v;
    a1 += smx[512 + s] * h0v + smx[513 + s] * h1v + smx[514 + s] * h2v + smx[515 + s] * h3v;
    a2 += smx[1024 + s] * h0v + smx[1025 + s] * h1v + smx[1026 + s] * h2v + smx[1027 + s] * h3v;
    a3 += smx[1536 + s] * h0v + smx[1537 + s] * h1v + smx[1538 + s] * h2v + smx[1539 + s] * h3v;
  }
  xcat0[b * 3072 + 512 + tid] = a0;
  xcat0[b * 3072 + 1024 + tid] = a1;
  xcat0[b * 3072 + 1536 + tid] = a2;
  xcat0[b * 3072 + 2048 + tid] = a3;
}

// ---- LSTM cell 0 epilogue: h0,c0; build xcat1; write next-step h0 slot ------
__global__ void k_act0(const float* __restrict__ part, const float* __restrict__ b_ih,
                       const float* __restrict__ b_hh, float* __restrict__ c0,
                       const float* __restrict__ h1_old, float* __restrict__ xcat1,
                       float* __restrict__ xcat0) {
  int idx = blockIdx.x * 256 + threadIdx.x;  // 16384
  int b = idx >> 9, hh = idx & 511;
  float g[4];
#pragma unroll
  for (int gi = 0; gi < 4; gi++) {
    int j = gi * 512 + hh;
    float v = b_ih[j] + b_hh[j];
#pragma unroll
    for (int sp = 0; sp < 8; sp++) v += part[(sp * 32 + b) * 2048 + j];
    g[gi] = v;
  }
  float i_ = sigmoidf_(g[0]), f_ = sigmoidf_(g[1]), gg = tanhf(g[2]), o_ = sigmoidf_(g[3]);
  float cn = f_ * c0[idx] + i_ * gg;
  float hn = o_ * tanhf(cn);
  c0[idx] = cn;
  xcat1[b * 1024 + hh] = hn;
  xcat1[b * 1024 + 512 + hh] = h1_old[idx];
  xcat0[b * 3072 + 2560 + hh] = hn;  // h0 slot for NEXT step's gates0
}

// ---- LSTM cell 1 epilogue: h1,c1; build xo = [h1_new | cvec] ----------------
__global__ void k_act1(const float* __restrict__ part, const float* __restrict__ b_ih,
                       const float* __restrict__ b_hh, float* __restrict__ c1,
                       float* __restrict__ h1, const float* __restrict__ xcat0,
                       float* __restrict__ xo) {
  int idx = blockIdx.x * 256 + threadIdx.x;  // 16384
  int b = idx >> 9, hh = idx & 511;
  float g[4];
#pragma unroll
  for (int gi = 0; gi < 4; gi++) {
    int j = gi * 512 + hh;
    float v = b_ih[j] + b_hh[j];
#pragma unroll
    for (int sp = 0; sp < 8; sp++) v += part[(sp * 32 + b) * 2048 + j];
    g[gi] = v;
  }
  float i_ = sigmoidf_(g[0]), f_ = sigmoidf_(g[1]), gg = tanhf(g[2]), o_ = sigmoidf_(g[3]);
  float cn = f_ * c1[idx] + i_ * gg;
  float hn = o_ * tanhf(cn);
  c1[idx] = cn;
  h1[idx] = hn;
  xo[b * 2560 + hh] = hn;
#pragma unroll
  for (int i = 0; i < 4; i++) {
    int kc = hh * 4 + i;
    xo[b * 2560 + 512 + kc] = xcat0[b * 3072 + 512 + kc];
  }
}

// ---- out = tanh( relu(sum partO + bo1) @ Wo2.T + bo2 ) ----------------------
// grid 16 blocks, each owns 32 output cols; o1 reduce fused in x-staging
__global__ void k_out2(const float* __restrict__ partO, const float* __restrict__ bo1,
                       const float* __restrict__ Wo2, const float* __restrict__ bo2,
                       float* __restrict__ outp, int t) {
  __shared__ float xs[32][65];
  __shared__ float ws[32][65];
  int tid = threadIdx.x;
  int j0 = blockIdx.x << 5;
  int jl = (tid & 15) << 1;
  int bl = (tid >> 4) << 1;
  int lr = tid >> 3, lk = (tid & 7) << 3;
  float acc[2][2] = {};
  for (int c = 0; c < 8; c++) {
    int k0 = c << 6;
    float xv[8];
#pragma unroll
    for (int i = 0; i < 8; i++) {
      int kk = k0 + lk + i;
      float v = bo1[kk];
#pragma unroll
      for (int sp = 0; sp < 8; sp++) v += partO[(sp * 32 + lr) * 512 + kk];
      xv[i] = fmaxf(v, 0.f);
    }
    float4 w0 = *(const float4*)&Wo2[(j0 + lr) * 512 + k0 + lk];
    float4 w1 = *(const float4*)&Wo2[(j0 + lr) * 512 + k0 + lk + 4];
    __syncthreads();
#pragma unroll
    for (int i = 0; i < 8; i++) xs[lr][lk + i] = xv[i];
    ws[lr][lk+0]=w0.x; ws[lr][lk+1]=w0.y; ws[lr][lk+2]=w0.z; ws[lr][lk+3]=w0.w;
    ws[lr][lk+4]=w1.x; ws[lr][lk+5]=w1.y; ws[lr][lk+6]=w1.z; ws[lr][lk+7]=w1.w;
    __syncthreads();
#pragma unroll 16
    for (int kk = 0; kk < 64; kk++) {
      float x0 = xs[bl][kk], x1 = xs[bl + 1][kk];
      float wa = ws[jl][kk], wb = ws[jl + 1][kk];
      acc[0][0] += x0 * wa; acc[0][1] += x0 * wb;
      acc[1][0] += x1 * wa; acc[1][1] += x1 * wb;
    }
  }
#pragma unroll
  for (int i = 0; i < 2; i++)
#pragma unroll
    for (int j = 0; j < 2; j++)
      outp[((bl + i) * 64 + t) * 512 + j0 + jl + j] = tanhf(acc[i][j] + bo2[j0 + jl + j]);
}

extern "C" void kernel_launch(void* const* d_in, const int* in_sizes, int n_in,
                              void* d_out, int out_size, void* d_ws, size_t ws_size,
                              hipStream_t stream) {
  const float* inputs  = (const float*)d_in[0];
  const int*   lengths = (const int*)d_in[1];
  const float* fh      = (const float*)d_in[2];
  const float* hiddens = (const float*)d_in[3];
  const float* Wa1     = (const float*)d_in[6];
  const float* ba1     = (const float*)d_in[7];
  const float* Wa2     = (const float*)d_in[8];
  const float* ba2     = (const float*)d_in[9];
  const float* W_ih0   = (const float*)d_in[10];
  const float* W_hh0   = (const float*)d_in[11];
  const float* b_ih0   = (const float*)d_in[12];
  const float* b_hh0   = (const float*)d_in[13];
  const float* W_ih1   = (const float*)d_in[14];
  const float* W_hh1   = (const float*)d_in[15];
  const float* b_ih1   = (const float*)d_in[16];
  const float* b_hh1   = (const float*)d_in[17];
  const float* Wo1     = (const float*)d_in[18];
  const float* bo1     = (const float*)d_in[19];
  const float* Wo2     = (const float*)d_in[20];
  const float* bo2     = (const float*)d_in[21];
  float* outp = (float*)d_out;

  float* p = (float*)d_ws;
  float* hp     = p; p += 16384 * 512;   // 32 MB
  float* scores = p; p += 65536;
  float* partA  = p; p += 8 * 32 * 2048;
  float* partQ  = p; p += 4 * 32 * 512;
  float* partO  = p; p += 8 * 32 * 512;
  float* h1     = p; p += 16384;
  float* c0     = p; p += 16384;
  float* c1     = p; p += 16384;
  float* xcat0  = p; p += 32 * 3072;
  float* xcat1  = p; p += 32 * 1024;
  float* xo     = p; p += 32 * 2560;

  k_init<<<64, 256, 0, stream>>>(fh, h1, c0, c1, xcat0);
  k_hidproj<<<dim3(256, 8), 256, 0, stream>>>(hiddens, Wa1, hp);

  for (int t = 0; t < 64; t++) {
    // q = h1 @ Wa1[:, :512].T  (J=512, K=512, 4 k-splits)
    k_skinny<<<dim3(8, 4), 256, 0, stream>>>(h1, 512, Wa1, 1024, Wa1, 1024, 512, 2, partQ, 512);
    k_scores<<<4096, 256, 0, stream>>>(hp, partQ, ba1, Wa2, ba2, lengths, scores);
    k_smcvec<<<32, 512, 0, stream>>>(scores, hiddens, inputs, t, xcat0);
    // gates0: xcat0[32][3072] @ [W_ih0|W_hh0].T  (J=2048, 8 splits x 6 chunks)
    k_skinny<<<dim3(32, 8), 256, 0, stream>>>(xcat0, 3072, W_ih0, 2560, W_hh0, 512, 2560, 6, partA, 2048);
    k_act0<<<64, 256, 0, stream>>>(partA, b_ih0, b_hh0, c0, h1, xcat1, xcat0);
    // gates1: xcat1[32][1024] @ [W_ih1|W_hh1].T  (J=2048, 8 splits x 2 chunks)
    k_skinny<<<dim3(32, 8), 256, 0, stream>>>(xcat1, 1024, W_ih1, 512, W_hh1, 512, 512, 2, partA, 2048);
    k_act1<<<64, 256, 0, stream>>>(partA, b_ih1, b_hh1, c1, h1, xcat0, xo);
    // o1 pre-activation: xo[32][2560] @ Wo1.T  (J=512, 8 splits x 5 chunks)
    k_skinny<<<dim3(8, 8), 256, 0, stream>>>(xo, 2560, Wo1, 2560, Wo1, 2560, 2560, 5, partO, 512);
    k_out2<<<16, 256, 0, stream>>>(partO, bo1, Wo2, bo2, outp, t);
  }
}